// Round 4
// baseline (779.344 us; speedup 1.0000x reference)
//
#include <hip/hip_runtime.h>
#include <math.h>

#define N_NODES 100000
#define N_EDGES 1600000
#define IN_FEATS 128
#define H_FEATS 64
#define SCAN_BLOCKS 391   // ceil(100000/256)

// ---------------- int degree histogram ----------------
__global__ __launch_bounds__(256) void hist_kernel(const int* __restrict__ dst,
                                                   int* __restrict__ degi) {
    int tid = blockIdx.x * 256 + threadIdx.x;
    int stride = gridDim.x * 256;
    for (int e = tid; e < N_EDGES; e += stride)
        atomicAdd(&degi[dst[e]], 1);
}

// degi -> dinv = 1/sqrt(max(deg,1))
__global__ __launch_bounds__(256) void dinv_kernel(const int* __restrict__ degi,
                                                   float* __restrict__ dinv) {
    int i = blockIdx.x * 256 + threadIdx.x;
    if (i < N_NODES) dinv[i] = rsqrtf(fmaxf((float)degi[i], 1.0f));
}

// ---------------- 3-kernel exclusive scan of degi -> rowp ----------------
__global__ __launch_bounds__(256) void scan1_kernel(const int* __restrict__ degi,
                                                    int* __restrict__ rowp,
                                                    int* __restrict__ bsums) {
    __shared__ int tmp[256];
    int i = blockIdx.x * 256 + threadIdx.x;
    int v = (i < N_NODES) ? degi[i] : 0;
    tmp[threadIdx.x] = v;
    __syncthreads();
    #pragma unroll
    for (int off = 1; off < 256; off <<= 1) {
        int t = (threadIdx.x >= off) ? tmp[threadIdx.x - off] : 0;
        __syncthreads();
        tmp[threadIdx.x] += t;
        __syncthreads();
    }
    if (i < N_NODES) rowp[i] = tmp[threadIdx.x] - v;
    if (threadIdx.x == 255) bsums[blockIdx.x] = tmp[255];
}

__global__ __launch_bounds__(512) void scan2_kernel(int* __restrict__ bsums) {
    __shared__ int tmp[512];
    int t = threadIdx.x;
    int v = (t < SCAN_BLOCKS) ? bsums[t] : 0;
    tmp[t] = v;
    __syncthreads();
    #pragma unroll
    for (int off = 1; off < 512; off <<= 1) {
        int x = (t >= off) ? tmp[t - off] : 0;
        __syncthreads();
        tmp[t] += x;
        __syncthreads();
    }
    if (t < SCAN_BLOCKS) bsums[t] = tmp[t] - v;
}

__global__ __launch_bounds__(256) void scan3_kernel(int* __restrict__ rowp,
                                                    const int* __restrict__ bsums) {
    int i = blockIdx.x * 256 + threadIdx.x;
    if (i < N_NODES) rowp[i] += bsums[blockIdx.x];
    if (i == N_NODES) rowp[N_NODES] = N_EDGES;
}

// ---------------- fill CSR slots with src indices + per-edge weight ----------------
__global__ __launch_bounds__(256) void fill_kernel(const int* __restrict__ src,
                                                   const int* __restrict__ dst,
                                                   const int* __restrict__ rowp,
                                                   const float* __restrict__ dinv,
                                                   int* __restrict__ cursor,
                                                   int* __restrict__ esrc,
                                                   float* __restrict__ esw) {
    int tid = blockIdx.x * 256 + threadIdx.x;
    int stride = gridDim.x * 256;
    for (int e = tid; e < N_EDGES; e += stride) {
        int d = dst[e];
        int s = src[e];
        int slot = rowp[d] + atomicAdd(&cursor[d], 1);
        esrc[slot] = s;
        esw[slot] = dinv[s];
    }
}

// ---------------- prep: weight transposes + theta-collapsed head weights ----------------
// WeffT[k][j][i] = sum_c thetas[c][k] * Wm1[c*64+i][j]
// W1T[j][i] = W1[i][j]   (64 x 128)
// W2T[j][i] = W2[i][j]   (64 x 64)
__global__ __launch_bounds__(256) void prep_kernel(const float* __restrict__ thetas,
                                                   const float* __restrict__ Wm1,
                                                   const float* __restrict__ W1,
                                                   const float* __restrict__ W2,
                                                   float* __restrict__ WeffT,
                                                   float* __restrict__ W1T,
                                                   float* __restrict__ W2T) {
    int t = blockIdx.x * 256 + threadIdx.x;
    if (t < 16384) {
        int k = t >> 12, ji = t & 4095, j = ji >> 6, i = ji & 63;
        float acc = 0.f;
        #pragma unroll
        for (int c = 0; c < 3; ++c)
            acc = fmaf(thetas[c * 4 + k], Wm1[(c * 64 + i) * 64 + j], acc);
        WeffT[t] = acc;
    } else if (t < 16384 + 8192) {
        int u = t - 16384, j = u >> 7, i = u & 127;
        W1T[u] = W1[i * 64 + j];
    } else if (t < 16384 + 8192 + 4096) {
        int u = t - 24576, j = u >> 6, i = u & 63;
        W2T[u] = W2[i * 64 + j];
    }
}

// ---------------- trunk: relu(relu(X@W1+b1)@W2+b2) — lane-owns-row ----------------
// wave w of block b owns rows [b*256 + w*64, +64); lane l owns one row.
// x in VGPRs (per-lane vector loads), weights via uniform s_load (K$-resident).
__global__ __launch_bounds__(256) void trunk_kernel(
    const float* __restrict__ X, const float* __restrict__ W1T, const float* __restrict__ b1,
    const float* __restrict__ W2T, const float* __restrict__ b2, float* __restrict__ H)
{
    int t = threadIdx.x;
    int lane = t & 63;
    int row0 = blockIdx.x * 256 + (t >> 6) * 64;
    int myrow = row0 + lane;
    int rle = (myrow < N_NODES) ? myrow : (N_NODES - 1);

    float y1[64];
    #pragma unroll
    for (int j = 0; j < 64; ++j) y1[j] = b1[j];

    #pragma unroll
    for (int ch = 0; ch < 2; ++ch) {
        float x[64];
        const float4* xp = (const float4*)(X + (size_t)rle * IN_FEATS + ch * 64);
        #pragma unroll
        for (int i4 = 0; i4 < 16; ++i4) {
            float4 v = xp[i4];
            x[4 * i4 + 0] = v.x; x[4 * i4 + 1] = v.y;
            x[4 * i4 + 2] = v.z; x[4 * i4 + 3] = v.w;
        }
        const float* wbase = W1T + ch * 64;
        #pragma unroll 2
        for (int j = 0; j < 64; ++j) {
            const float* w = wbase + j * IN_FEATS;   // uniform addr -> s_load
            float a = 0.f, b = 0.f;
            #pragma unroll
            for (int i = 0; i < 64; i += 2) {
                a = fmaf(x[i],     w[i],     a);
                b = fmaf(x[i + 1], w[i + 1], b);
            }
            y1[j] += a + b;
        }
    }
    float h[64];
    #pragma unroll
    for (int j = 0; j < 64; ++j) h[j] = fmaxf(y1[j], 0.f);

    float y2[64];
    #pragma unroll 2
    for (int j = 0; j < 64; ++j) {
        const float* w = W2T + j * 64;               // uniform addr -> s_load
        float a = b2[j], b = 0.f;
        #pragma unroll
        for (int i = 0; i < 64; i += 2) {
            a = fmaf(h[i],     w[i],     a);
            b = fmaf(h[i + 1], w[i + 1], b);
        }
        y2[j] = fmaxf(a + b, 0.f);
    }
    if (myrow < N_NODES) {
        float4* hp = (float4*)(H + (size_t)myrow * 64);
        #pragma unroll
        for (int j4 = 0; j4 < 16; ++j4)
            hp[j4] = make_float4(y2[4 * j4], y2[4 * j4 + 1], y2[4 * j4 + 2], y2[4 * j4 + 3]);
    }
}

// ---------------- gather pass: Fnew[n] = Fprev[n] - dinv[n]*sum_e esw[e]*Fprev[esrc[e]]
// one wave per node, lane = feature dim; esrc/esw are independent uniform s_loads
__global__ __launch_bounds__(256) void gather_kernel(
    const float* __restrict__ Fprev, const int* __restrict__ rowp,
    const int* __restrict__ esrc, const float* __restrict__ esw,
    const float* __restrict__ dinv, float* __restrict__ Fnew)
{
    int wv = __builtin_amdgcn_readfirstlane(threadIdx.x >> 6);
    int wid = blockIdx.x * 4 + wv;   // node id (uniform)
    int lane = threadIdx.x & 63;
    int beg = rowp[wid], end = rowp[wid + 1];
    float acc = 0.0f;
    int j = beg;
    for (; j + 7 < end; j += 8) {
        int s0 = esrc[j],     s1 = esrc[j + 1], s2 = esrc[j + 2], s3 = esrc[j + 3];
        int s4 = esrc[j + 4], s5 = esrc[j + 5], s6 = esrc[j + 6], s7 = esrc[j + 7];
        float w0 = esw[j],     w1 = esw[j + 1], w2 = esw[j + 2], w3 = esw[j + 3];
        float w4 = esw[j + 4], w5 = esw[j + 5], w6 = esw[j + 6], w7 = esw[j + 7];
        float v0 = Fprev[(size_t)s0 * 64 + lane];
        float v1 = Fprev[(size_t)s1 * 64 + lane];
        float v2 = Fprev[(size_t)s2 * 64 + lane];
        float v3 = Fprev[(size_t)s3 * 64 + lane];
        float v4 = Fprev[(size_t)s4 * 64 + lane];
        float v5 = Fprev[(size_t)s5 * 64 + lane];
        float v6 = Fprev[(size_t)s6 * 64 + lane];
        float v7 = Fprev[(size_t)s7 * 64 + lane];
        acc = fmaf(v0, w0, acc);
        acc = fmaf(v1, w1, acc);
        acc = fmaf(v2, w2, acc);
        acc = fmaf(v3, w3, acc);
        acc = fmaf(v4, w4, acc);
        acc = fmaf(v5, w5, acc);
        acc = fmaf(v6, w6, acc);
        acc = fmaf(v7, w7, acc);
    }
    for (; j < end; ++j) {
        acc = fmaf(Fprev[(size_t)esrc[j] * 64 + lane], esw[j], acc);
    }
    float di = dinv[wid];
    Fnew[(size_t)wid * 64 + lane] = Fprev[(size_t)wid * 64 + lane] - acc * di;
}

// ---------------- final: out = relu(sum_k Lk @ Weff[k] + bm1) @ Wm2 + bm2 ----------------
// lane-owns-row: x (Lk row) in 64 VGPRs, WeffT columns via uniform s_load.
__global__ __launch_bounds__(256) void final_kernel(
    const float* __restrict__ L0, const float* __restrict__ L1,
    const float* __restrict__ L2, const float* __restrict__ L3,
    const float* __restrict__ WeffT, const float* __restrict__ Wm2,
    const float* __restrict__ bm1, const float* __restrict__ bm2,
    float* __restrict__ out)
{
    int t = threadIdx.x;
    int lane = t & 63;
    int row0 = blockIdx.x * 256 + (t >> 6) * 64;
    int myrow = row0 + lane;
    int rle = (myrow < N_NODES) ? myrow : (N_NODES - 1);

    float y[64];
    #pragma unroll
    for (int j = 0; j < 64; ++j) y[j] = bm1[j];

    const float* Ls[4] = {L0, L1, L2, L3};
    #pragma unroll
    for (int k = 0; k < 4; ++k) {
        float x[64];
        const float4* xp = (const float4*)(Ls[k] + (size_t)rle * 64);
        #pragma unroll
        for (int i4 = 0; i4 < 16; ++i4) {
            float4 v = xp[i4];
            x[4 * i4 + 0] = v.x; x[4 * i4 + 1] = v.y;
            x[4 * i4 + 2] = v.z; x[4 * i4 + 3] = v.w;
        }
        const float* wt = WeffT + k * 4096;
        #pragma unroll 2
        for (int j = 0; j < 64; ++j) {
            const float* w = wt + j * 64;            // uniform addr -> s_load
            float a = 0.f, b = 0.f;
            #pragma unroll
            for (int i = 0; i < 64; i += 2) {
                a = fmaf(x[i],     w[i],     a);
                b = fmaf(x[i + 1], w[i + 1], b);
            }
            y[j] += a + b;
        }
    }
    float o0 = bm2[0], o1 = bm2[1];
    #pragma unroll
    for (int j = 0; j < 64; ++j) {
        float v = fmaxf(y[j], 0.f);
        o0 = fmaf(v, Wm2[2 * j + 0], o0);
        o1 = fmaf(v, Wm2[2 * j + 1], o1);
    }
    if (myrow < N_NODES) {
        out[myrow * 2 + 0] = o0;
        out[myrow * 2 + 1] = o1;
    }
}

extern "C" void kernel_launch(void* const* d_in, const int* in_sizes, int n_in,
                              void* d_out, int out_size, void* d_ws, size_t ws_size,
                              hipStream_t stream)
{
    const float* feature = (const float*)d_in[0];
    const int*   src     = (const int*)d_in[1];
    const int*   dst     = (const int*)d_in[2];
    const float* W1      = (const float*)d_in[3];
    const float* b1      = (const float*)d_in[4];
    const float* W2      = (const float*)d_in[5];
    const float* b2      = (const float*)d_in[6];
    const float* thetas  = (const float*)d_in[7];
    const float* Wm1     = (const float*)d_in[8];
    const float* bm1     = (const float*)d_in[9];
    const float* Wm2     = (const float*)d_in[10];
    const float* bm2     = (const float*)d_in[11];
    float* out = (float*)d_out;

    const size_t NH = (size_t)N_NODES * H_FEATS;   // 6.4M floats
    const int NPAD = 100352;
    float* dinv   = (float*)d_ws;                   // N
    int*   degi   = (int*)(dinv + NPAD);            // N
    int*   rowp   = degi + NPAD;                    // N+1
    int*   bsums  = rowp + NPAD;                    // 512
    int*   cursor = bsums + 512;                    // N
    int*   esrc   = cursor + NPAD;                  // E
    float* esw    = (float*)(esrc + N_EDGES);       // E
    float* L0     = esw + N_EDGES;
    float* L1     = L0 + NH;
    float* L2     = L1 + NH;
    float* L3     = L2 + NH;
    float* WeffT  = L3 + NH;                        // 16384
    float* W1T    = WeffT + 16384;                  // 8192
    float* W2T    = W1T + 8192;                     // 4096
    // total ws use ≈ 117 MB

    hipMemsetAsync(degi,   0, N_NODES * sizeof(int), stream);
    hipMemsetAsync(cursor, 0, N_NODES * sizeof(int), stream);

    hist_kernel<<<1024, 256, 0, stream>>>(dst, degi);
    dinv_kernel<<<(N_NODES + 255) / 256, 256, 0, stream>>>(degi, dinv);
    scan1_kernel<<<SCAN_BLOCKS, 256, 0, stream>>>(degi, rowp, bsums);
    scan2_kernel<<<1, 512, 0, stream>>>(bsums);
    scan3_kernel<<<SCAN_BLOCKS, 256, 0, stream>>>(rowp, bsums);
    fill_kernel<<<1024, 256, 0, stream>>>(src, dst, rowp, dinv, cursor, esrc, esw);

    prep_kernel<<<112, 256, 0, stream>>>(thetas, Wm1, W1, W2, WeffT, W1T, W2T);
    trunk_kernel<<<391, 256, 0, stream>>>(feature, W1T, b1, W2T, b2, L0);

    float* Ls[4] = {L0, L1, L2, L3};
    for (int k = 1; k <= 3; ++k)
        gather_kernel<<<25000, 256, 0, stream>>>(Ls[k - 1], rowp, esrc, esw, dinv, Ls[k]);

    final_kernel<<<391, 256, 0, stream>>>(L0, L1, L2, L3, WeffT, Wm2, bm1, bm2, out);
}

// Round 5
// 518.307 us; speedup vs baseline: 1.5036x; 1.5036x over previous
//
#include <hip/hip_runtime.h>
#include <math.h>

#define N_NODES 100000
#define N_EDGES 1600000
#define IN_FEATS 128
#define H_FEATS 64
#define SCAN_BLOCKS 391   // ceil(100000/256)

// ---------------- int degree histogram ----------------
__global__ __launch_bounds__(256) void hist_kernel(const int* __restrict__ dst,
                                                   int* __restrict__ degi) {
    int tid = blockIdx.x * 256 + threadIdx.x;
    int stride = gridDim.x * 256;
    for (int e = tid; e < N_EDGES; e += stride)
        atomicAdd(&degi[dst[e]], 1);
}

// degi -> dinv = 1/sqrt(max(deg,1))
__global__ __launch_bounds__(256) void dinv_kernel(const int* __restrict__ degi,
                                                   float* __restrict__ dinv) {
    int i = blockIdx.x * 256 + threadIdx.x;
    if (i < N_NODES) dinv[i] = rsqrtf(fmaxf((float)degi[i], 1.0f));
}

// ---------------- 3-kernel exclusive scan of degi -> rowp ----------------
__global__ __launch_bounds__(256) void scan1_kernel(const int* __restrict__ degi,
                                                    int* __restrict__ rowp,
                                                    int* __restrict__ bsums) {
    __shared__ int tmp[256];
    int i = blockIdx.x * 256 + threadIdx.x;
    int v = (i < N_NODES) ? degi[i] : 0;
    tmp[threadIdx.x] = v;
    __syncthreads();
    #pragma unroll
    for (int off = 1; off < 256; off <<= 1) {
        int t = (threadIdx.x >= off) ? tmp[threadIdx.x - off] : 0;
        __syncthreads();
        tmp[threadIdx.x] += t;
        __syncthreads();
    }
    if (i < N_NODES) rowp[i] = tmp[threadIdx.x] - v;
    if (threadIdx.x == 255) bsums[blockIdx.x] = tmp[255];
}

__global__ __launch_bounds__(512) void scan2_kernel(int* __restrict__ bsums) {
    __shared__ int tmp[512];
    int t = threadIdx.x;
    int v = (t < SCAN_BLOCKS) ? bsums[t] : 0;
    tmp[t] = v;
    __syncthreads();
    #pragma unroll
    for (int off = 1; off < 512; off <<= 1) {
        int x = (t >= off) ? tmp[t - off] : 0;
        __syncthreads();
        tmp[t] += x;
        __syncthreads();
    }
    if (t < SCAN_BLOCKS) bsums[t] = tmp[t] - v;
}

__global__ __launch_bounds__(256) void scan3_kernel(int* __restrict__ rowp,
                                                    const int* __restrict__ bsums) {
    int i = blockIdx.x * 256 + threadIdx.x;
    if (i < N_NODES) rowp[i] += bsums[blockIdx.x];
    if (i == N_NODES) rowp[N_NODES] = N_EDGES;
}

// ---------------- fill CSR slots with src indices + per-edge weight ----------------
__global__ __launch_bounds__(256) void fill_kernel(const int* __restrict__ src,
                                                   const int* __restrict__ dst,
                                                   const int* __restrict__ rowp,
                                                   const float* __restrict__ dinv,
                                                   int* __restrict__ cursor,
                                                   int* __restrict__ esrc,
                                                   float* __restrict__ esw) {
    int tid = blockIdx.x * 256 + threadIdx.x;
    int stride = gridDim.x * 256;
    for (int e = tid; e < N_EDGES; e += stride) {
        int d = dst[e];
        int s = src[e];
        int slot = rowp[d] + atomicAdd(&cursor[d], 1);
        esrc[slot] = s;
        esw[slot] = dinv[s];
    }
}

// ---------------- Weff[k][i][j] = sum_c thetas[c][k] * Wm1[c*64+i][j] ----------------
__global__ __launch_bounds__(256) void weff_kernel(const float* __restrict__ thetas,
                                                   const float* __restrict__ Wm1,
                                                   float* __restrict__ Weff) {
    int t = blockIdx.x * 256 + threadIdx.x;  // 16384 total
    int k = t >> 12, ij = t & 4095, i = ij >> 6, j = ij & 63;
    float acc = 0.f;
    #pragma unroll
    for (int c = 0; c < 3; ++c)
        acc = fmaf(thetas[c * 4 + k], Wm1[(c * 64 + i) * 64 + j], acc);
    Weff[t] = acc;
}

// ---------------- trunk: relu(relu(X@W1+b1)@W2+b2) ----------------
// 64 rows/block, 4 batches of 16. K split across 4 waves; weights in VGPRs
// (w1r[32], w2r[16]); activations LDS-staged via coalesced float4 loads and
// read back as wave-uniform broadcast ds_read_b128. Cross-wave reduce in LDS.
__global__ __launch_bounds__(256) void trunk_kernel(
    const float* __restrict__ X, const float* __restrict__ W1, const float* __restrict__ b1,
    const float* __restrict__ W2, const float* __restrict__ b2, float* __restrict__ H)
{
    __shared__ float stage[16][IN_FEATS];   // 8 KB
    __shared__ float part[4][16][64];       // 16 KB
    __shared__ float h1s[16][64];           // 4 KB
    int t = threadIdx.x;
    int wv = __builtin_amdgcn_readfirstlane(t >> 6);
    int lane = t & 63;
    float w1r[32], w2r[16];
    #pragma unroll
    for (int i = 0; i < 32; ++i) w1r[i] = W1[(wv * 32 + i) * 64 + lane];
    #pragma unroll
    for (int i = 0; i < 16; ++i) w2r[i] = W2[(wv * 16 + i) * 64 + lane];
    float b1v = b1[lane], b2v = b2[lane];
    int sr = t >> 4, sc = t & 15;           // staging: row sr, 8-float chunk sc

    for (int batch = 0; batch < 4; ++batch) {
        int row0 = blockIdx.x * 64 + batch * 16;
        {
            int row = row0 + sr; if (row >= N_NODES) row = N_NODES - 1;
            const float4* s4 = (const float4*)(X + (size_t)row * IN_FEATS + sc * 8);
            float4* d4 = (float4*)&stage[sr][sc * 8];
            d4[0] = s4[0]; d4[1] = s4[1];
        }
        __syncthreads();
        // layer 1: acc[r] = x[r][wv*32 .. +32] . w1r
        float acc[16];
        #pragma unroll
        for (int r = 0; r < 16; ++r) {
            const float4* xb = (const float4*)&stage[r][wv * 32];   // uniform -> broadcast
            float a = 0.f, b = 0.f;
            #pragma unroll
            for (int i4 = 0; i4 < 8; i4 += 2) {
                float4 v0 = xb[i4], v1 = xb[i4 + 1];
                a = fmaf(v0.x, w1r[i4 * 4 + 0], a);
                a = fmaf(v0.y, w1r[i4 * 4 + 1], a);
                a = fmaf(v0.z, w1r[i4 * 4 + 2], a);
                a = fmaf(v0.w, w1r[i4 * 4 + 3], a);
                b = fmaf(v1.x, w1r[i4 * 4 + 4], b);
                b = fmaf(v1.y, w1r[i4 * 4 + 5], b);
                b = fmaf(v1.z, w1r[i4 * 4 + 6], b);
                b = fmaf(v1.w, w1r[i4 * 4 + 7], b);
            }
            acc[r] = a + b;
        }
        #pragma unroll
        for (int r = 0; r < 16; ++r) part[wv][r][lane] = acc[r];
        __syncthreads();
        // h1 build: wave wv reduces rows wv*4 .. wv*4+3
        #pragma unroll
        for (int rr = 0; rr < 4; ++rr) {
            int r = wv * 4 + rr;
            float y1 = part[0][r][lane] + part[1][r][lane] +
                       part[2][r][lane] + part[3][r][lane] + b1v;
            h1s[r][lane] = fmaxf(y1, 0.f);
        }
        __syncthreads();
        // layer 2: acc2[r] = h1[r][wv*16 .. +16] . w2r
        float acc2[16];
        #pragma unroll
        for (int r = 0; r < 16; ++r) {
            const float4* xb = (const float4*)&h1s[r][wv * 16];     // uniform -> broadcast
            float a = 0.f, b = 0.f;
            #pragma unroll
            for (int i4 = 0; i4 < 4; i4 += 2) {
                float4 v0 = xb[i4], v1 = xb[i4 + 1];
                a = fmaf(v0.x, w2r[i4 * 4 + 0], a);
                a = fmaf(v0.y, w2r[i4 * 4 + 1], a);
                a = fmaf(v0.z, w2r[i4 * 4 + 2], a);
                a = fmaf(v0.w, w2r[i4 * 4 + 3], a);
                b = fmaf(v1.x, w2r[i4 * 4 + 4], b);
                b = fmaf(v1.y, w2r[i4 * 4 + 5], b);
                b = fmaf(v1.z, w2r[i4 * 4 + 6], b);
                b = fmaf(v1.w, w2r[i4 * 4 + 7], b);
            }
            acc2[r] = a + b;
        }
        __syncthreads();   // all h1s reads done; part reads (h1 build) done
        #pragma unroll
        for (int r = 0; r < 16; ++r) part[wv][r][lane] = acc2[r];
        __syncthreads();
        #pragma unroll
        for (int rr = 0; rr < 4; ++rr) {
            int r = wv * 4 + rr;
            int row = row0 + r;
            float y2 = part[0][r][lane] + part[1][r][lane] +
                       part[2][r][lane] + part[3][r][lane] + b2v;
            if (row < N_NODES) H[(size_t)row * 64 + lane] = fmaxf(y2, 0.f);
        }
        __syncthreads();   // protect stage/part/h1s before next batch
    }
}

// ---------------- gather pass: Fnew[n] = Fprev[n] - dinv[n]*sum_e esw[e]*Fprev[esrc[e]]
__global__ __launch_bounds__(256) void gather_kernel(
    const float* __restrict__ Fprev, const int* __restrict__ rowp,
    const int* __restrict__ esrc, const float* __restrict__ esw,
    const float* __restrict__ dinv, float* __restrict__ Fnew)
{
    int wv = __builtin_amdgcn_readfirstlane(threadIdx.x >> 6);
    int wid = blockIdx.x * 4 + wv;   // node id (uniform)
    int lane = threadIdx.x & 63;
    int beg = rowp[wid], end = rowp[wid + 1];
    float acc = 0.0f;
    int j = beg;
    for (; j + 7 < end; j += 8) {
        int s0 = esrc[j],     s1 = esrc[j + 1], s2 = esrc[j + 2], s3 = esrc[j + 3];
        int s4 = esrc[j + 4], s5 = esrc[j + 5], s6 = esrc[j + 6], s7 = esrc[j + 7];
        float w0 = esw[j],     w1 = esw[j + 1], w2 = esw[j + 2], w3 = esw[j + 3];
        float w4 = esw[j + 4], w5 = esw[j + 5], w6 = esw[j + 6], w7 = esw[j + 7];
        float v0 = Fprev[(size_t)s0 * 64 + lane];
        float v1 = Fprev[(size_t)s1 * 64 + lane];
        float v2 = Fprev[(size_t)s2 * 64 + lane];
        float v3 = Fprev[(size_t)s3 * 64 + lane];
        float v4 = Fprev[(size_t)s4 * 64 + lane];
        float v5 = Fprev[(size_t)s5 * 64 + lane];
        float v6 = Fprev[(size_t)s6 * 64 + lane];
        float v7 = Fprev[(size_t)s7 * 64 + lane];
        acc = fmaf(v0, w0, acc);
        acc = fmaf(v1, w1, acc);
        acc = fmaf(v2, w2, acc);
        acc = fmaf(v3, w3, acc);
        acc = fmaf(v4, w4, acc);
        acc = fmaf(v5, w5, acc);
        acc = fmaf(v6, w6, acc);
        acc = fmaf(v7, w7, acc);
    }
    for (; j < end; ++j) {
        acc = fmaf(Fprev[(size_t)esrc[j] * 64 + lane], esw[j], acc);
    }
    float di = dinv[wid];
    Fnew[(size_t)wid * 64 + lane] = Fprev[(size_t)wid * 64 + lane] - acc * di;
}

// ---------------- final: out = relu(sum_k Lk @ Weff[k] + bm1) @ Wm2 + bm2 ----------------
// 64 rows/block, 4 batches of 16. Wave wv owns K-slice k=wv with Weff[wv] in
// 64 VGPRs; activations LDS-staged (coalesced float4 in, broadcast b128 out).
__global__ __launch_bounds__(256) void final_kernel(
    const float* __restrict__ L0, const float* __restrict__ L1,
    const float* __restrict__ L2, const float* __restrict__ L3,
    const float* __restrict__ Weff, const float* __restrict__ Wm2,
    const float* __restrict__ bm1, const float* __restrict__ bm2,
    float* __restrict__ out)
{
    __shared__ float stage[16][4][64];   // 16 KB: [row][k][feat]
    __shared__ float part[4][16][64];    // 16 KB
    int t = threadIdx.x;
    int wv = __builtin_amdgcn_readfirstlane(t >> 6);
    int lane = t & 63;
    float wreg[64];
    #pragma unroll
    for (int i = 0; i < 64; ++i)
        wreg[i] = Weff[wv * 4096 + i * 64 + lane];   // Weff[k=wv][i][col=lane]
    float b1v = bm1[lane];
    float wm20 = Wm2[lane * 2 + 0], wm21 = Wm2[lane * 2 + 1];
    float bm20 = bm2[0], bm21 = bm2[1];
    const float* Ls[4] = {L0, L1, L2, L3};
    int sr = t >> 4, sc = t & 15;
    int sk = sc >> 2, so = (sc & 3) * 16;   // thread stages 16 floats of matrix sk

    for (int batch = 0; batch < 4; ++batch) {
        int row0 = blockIdx.x * 64 + batch * 16;
        {
            int row = row0 + sr; if (row >= N_NODES) row = N_NODES - 1;
            const float4* s4 = (const float4*)(Ls[sk] + (size_t)row * 64 + so);
            float4* d4 = (float4*)&stage[sr][sk][so];
            #pragma unroll
            for (int q = 0; q < 4; ++q) d4[q] = s4[q];
        }
        __syncthreads();
        float acc[16];
        #pragma unroll
        for (int r = 0; r < 16; ++r) {
            const float4* xb = (const float4*)&stage[r][wv][0];   // uniform -> broadcast
            float a = 0.f, b = 0.f;
            #pragma unroll
            for (int i4 = 0; i4 < 16; i4 += 2) {
                float4 v0 = xb[i4], v1 = xb[i4 + 1];
                a = fmaf(v0.x, wreg[i4 * 4 + 0], a);
                a = fmaf(v0.y, wreg[i4 * 4 + 1], a);
                a = fmaf(v0.z, wreg[i4 * 4 + 2], a);
                a = fmaf(v0.w, wreg[i4 * 4 + 3], a);
                b = fmaf(v1.x, wreg[i4 * 4 + 4], b);
                b = fmaf(v1.y, wreg[i4 * 4 + 5], b);
                b = fmaf(v1.z, wreg[i4 * 4 + 6], b);
                b = fmaf(v1.w, wreg[i4 * 4 + 7], b);
            }
            acc[r] = a + b;
        }
        #pragma unroll
        for (int r = 0; r < 16; ++r) part[wv][r][lane] = acc[r];
        __syncthreads();
        // wave wv finishes rows wv*4 .. wv*4+3: reduce, relu, head GEMV
        #pragma unroll
        for (int rr = 0; rr < 4; ++rr) {
            int r = wv * 4 + rr;
            int row = row0 + r;
            float y = part[0][r][lane] + part[1][r][lane] +
                      part[2][r][lane] + part[3][r][lane] + b1v;
            y = fmaxf(y, 0.f);
            float o0 = y * wm20;
            float o1 = y * wm21;
            #pragma unroll
            for (int off = 32; off > 0; off >>= 1) {
                o0 += __shfl_down(o0, off);
                o1 += __shfl_down(o1, off);
            }
            if (lane == 0 && row < N_NODES) {
                out[row * 2 + 0] = o0 + bm20;
                out[row * 2 + 1] = o1 + bm21;
            }
        }
        __syncthreads();
    }
}

extern "C" void kernel_launch(void* const* d_in, const int* in_sizes, int n_in,
                              void* d_out, int out_size, void* d_ws, size_t ws_size,
                              hipStream_t stream)
{
    const float* feature = (const float*)d_in[0];
    const int*   src     = (const int*)d_in[1];
    const int*   dst     = (const int*)d_in[2];
    const float* W1      = (const float*)d_in[3];
    const float* b1      = (const float*)d_in[4];
    const float* W2      = (const float*)d_in[5];
    const float* b2      = (const float*)d_in[6];
    const float* thetas  = (const float*)d_in[7];
    const float* Wm1     = (const float*)d_in[8];
    const float* bm1     = (const float*)d_in[9];
    const float* Wm2     = (const float*)d_in[10];
    const float* bm2     = (const float*)d_in[11];
    float* out = (float*)d_out;

    const size_t NH = (size_t)N_NODES * H_FEATS;   // 6.4M floats
    const int NPAD = 100352;
    float* dinv   = (float*)d_ws;                   // N
    int*   degi   = (int*)(dinv + NPAD);            // N
    int*   rowp   = degi + NPAD;                    // N+1
    int*   bsums  = rowp + NPAD;                    // 512
    int*   cursor = bsums + 512;                    // N
    int*   esrc   = cursor + NPAD;                  // E
    float* esw    = (float*)(esrc + N_EDGES);       // E
    float* L0     = esw + N_EDGES;
    float* L1     = L0 + NH;
    float* L2     = L1 + NH;
    float* L3     = L2 + NH;
    float* Weff   = L3 + NH;                        // 16384
    // total ws use ≈ 117 MB

    hipMemsetAsync(degi,   0, N_NODES * sizeof(int), stream);
    hipMemsetAsync(cursor, 0, N_NODES * sizeof(int), stream);

    hist_kernel<<<1024, 256, 0, stream>>>(dst, degi);
    dinv_kernel<<<(N_NODES + 255) / 256, 256, 0, stream>>>(degi, dinv);
    scan1_kernel<<<SCAN_BLOCKS, 256, 0, stream>>>(degi, rowp, bsums);
    scan2_kernel<<<1, 512, 0, stream>>>(bsums);
    scan3_kernel<<<SCAN_BLOCKS, 256, 0, stream>>>(rowp, bsums);
    fill_kernel<<<1024, 256, 0, stream>>>(src, dst, rowp, dinv, cursor, esrc, esw);

    weff_kernel<<<64, 256, 0, stream>>>(thetas, Wm1, Weff);
    trunk_kernel<<<1563, 256, 0, stream>>>(feature, W1, b1, W2, b2, L0);

    float* Ls[4] = {L0, L1, L2, L3};
    for (int k = 1; k <= 3; ++k)
        gather_kernel<<<25000, 256, 0, stream>>>(Ls[k - 1], rowp, esrc, esw, dinv, Ls[k]);

    final_kernel<<<1563, 256, 0, stream>>>(L0, L1, L2, L3, Weff, Wm2, bm1, bm2, out);
}

// Round 6
// 490.680 us; speedup vs baseline: 1.5883x; 1.0563x over previous
//
#include <hip/hip_runtime.h>
#include <math.h>

#define N_NODES 100000
#define N_EDGES 1600000
#define IN_FEATS 128
#define H_FEATS 64
#define SCAN_BLOCKS 391   // ceil(100000/256)

// ---------------- int degree histogram ----------------
__global__ __launch_bounds__(256) void hist_kernel(const int* __restrict__ dst,
                                                   int* __restrict__ degi) {
    int tid = blockIdx.x * 256 + threadIdx.x;
    int stride = gridDim.x * 256;
    for (int e = tid; e < N_EDGES; e += stride)
        atomicAdd(&degi[dst[e]], 1);
}

// degi -> dinv = 1/sqrt(max(deg,1))
__global__ __launch_bounds__(256) void dinv_kernel(const int* __restrict__ degi,
                                                   float* __restrict__ dinv) {
    int i = blockIdx.x * 256 + threadIdx.x;
    if (i < N_NODES) dinv[i] = rsqrtf(fmaxf((float)degi[i], 1.0f));
}

// ---------------- 3-kernel exclusive scan of degi -> rowp ----------------
__global__ __launch_bounds__(256) void scan1_kernel(const int* __restrict__ degi,
                                                    int* __restrict__ rowp,
                                                    int* __restrict__ bsums) {
    __shared__ int tmp[256];
    int i = blockIdx.x * 256 + threadIdx.x;
    int v = (i < N_NODES) ? degi[i] : 0;
    tmp[threadIdx.x] = v;
    __syncthreads();
    #pragma unroll
    for (int off = 1; off < 256; off <<= 1) {
        int t = (threadIdx.x >= off) ? tmp[threadIdx.x - off] : 0;
        __syncthreads();
        tmp[threadIdx.x] += t;
        __syncthreads();
    }
    if (i < N_NODES) rowp[i] = tmp[threadIdx.x] - v;
    if (threadIdx.x == 255) bsums[blockIdx.x] = tmp[255];
}

__global__ __launch_bounds__(512) void scan2_kernel(int* __restrict__ bsums) {
    __shared__ int tmp[512];
    int t = threadIdx.x;
    int v = (t < SCAN_BLOCKS) ? bsums[t] : 0;
    tmp[t] = v;
    __syncthreads();
    #pragma unroll
    for (int off = 1; off < 512; off <<= 1) {
        int x = (t >= off) ? tmp[t - off] : 0;
        __syncthreads();
        tmp[t] += x;
        __syncthreads();
    }
    if (t < SCAN_BLOCKS) bsums[t] = tmp[t] - v;
}

__global__ __launch_bounds__(256) void scan3_kernel(int* __restrict__ rowp,
                                                    const int* __restrict__ bsums) {
    int i = blockIdx.x * 256 + threadIdx.x;
    if (i < N_NODES) rowp[i] += bsums[blockIdx.x];
    if (i == N_NODES) rowp[N_NODES] = N_EDGES;
}

// ---------------- fill CSR slots: single packed 8B write per edge ----------------
// epack[slot] = {src, bits(dinv[src])}
__global__ __launch_bounds__(256) void fill_kernel(const int* __restrict__ src,
                                                   const int* __restrict__ dst,
                                                   const int* __restrict__ rowp,
                                                   const float* __restrict__ dinv,
                                                   int* __restrict__ cursor,
                                                   int2* __restrict__ epack) {
    int tid = blockIdx.x * 256 + threadIdx.x;
    int stride = gridDim.x * 256;
    for (int e = tid; e < N_EDGES; e += stride) {
        int d = dst[e];
        int s = src[e];
        int slot = rowp[d] + atomicAdd(&cursor[d], 1);
        epack[slot] = make_int2(s, __float_as_int(dinv[s]));
    }
}

// ---------------- Weff[k][i][j] = sum_c thetas[c][k] * Wm1[c*64+i][j] ----------------
__global__ __launch_bounds__(256) void weff_kernel(const float* __restrict__ thetas,
                                                   const float* __restrict__ Wm1,
                                                   float* __restrict__ Weff) {
    int t = blockIdx.x * 256 + threadIdx.x;  // 16384 total
    int k = t >> 12, ij = t & 4095, i = ij >> 6, j = ij & 63;
    float acc = 0.f;
    #pragma unroll
    for (int c = 0; c < 3; ++c)
        acc = fmaf(thetas[c * 4 + k], Wm1[(c * 64 + i) * 64 + j], acc);
    Weff[t] = acc;
}

// ---------------- trunk: relu(relu(X@W1+b1)@W2+b2) ----------------
// 64 rows/block, 4 batches of 16. K split across 4 waves; weights in VGPRs;
// activations LDS-staged (coalesced float4 in, wave-uniform broadcast b128 out).
__global__ __launch_bounds__(256) void trunk_kernel(
    const float* __restrict__ X, const float* __restrict__ W1, const float* __restrict__ b1,
    const float* __restrict__ W2, const float* __restrict__ b2, float* __restrict__ H)
{
    __shared__ float stage[16][IN_FEATS];   // 8 KB
    __shared__ float part[4][16][64];       // 16 KB
    __shared__ float h1s[16][64];           // 4 KB
    int t = threadIdx.x;
    int wv = __builtin_amdgcn_readfirstlane(t >> 6);
    int lane = t & 63;
    float w1r[32], w2r[16];
    #pragma unroll
    for (int i = 0; i < 32; ++i) w1r[i] = W1[(wv * 32 + i) * 64 + lane];
    #pragma unroll
    for (int i = 0; i < 16; ++i) w2r[i] = W2[(wv * 16 + i) * 64 + lane];
    float b1v = b1[lane], b2v = b2[lane];
    int sr = t >> 4, sc = t & 15;           // staging: row sr, 8-float chunk sc

    for (int batch = 0; batch < 4; ++batch) {
        int row0 = blockIdx.x * 64 + batch * 16;
        {
            int row = row0 + sr; if (row >= N_NODES) row = N_NODES - 1;
            const float4* s4 = (const float4*)(X + (size_t)row * IN_FEATS + sc * 8);
            float4* d4 = (float4*)&stage[sr][sc * 8];
            d4[0] = s4[0]; d4[1] = s4[1];
        }
        __syncthreads();
        float acc[16];
        #pragma unroll
        for (int r = 0; r < 16; ++r) {
            const float4* xb = (const float4*)&stage[r][wv * 32];   // uniform -> broadcast
            float a = 0.f, b = 0.f;
            #pragma unroll
            for (int i4 = 0; i4 < 8; i4 += 2) {
                float4 v0 = xb[i4], v1 = xb[i4 + 1];
                a = fmaf(v0.x, w1r[i4 * 4 + 0], a);
                a = fmaf(v0.y, w1r[i4 * 4 + 1], a);
                a = fmaf(v0.z, w1r[i4 * 4 + 2], a);
                a = fmaf(v0.w, w1r[i4 * 4 + 3], a);
                b = fmaf(v1.x, w1r[i4 * 4 + 4], b);
                b = fmaf(v1.y, w1r[i4 * 4 + 5], b);
                b = fmaf(v1.z, w1r[i4 * 4 + 6], b);
                b = fmaf(v1.w, w1r[i4 * 4 + 7], b);
            }
            acc[r] = a + b;
        }
        #pragma unroll
        for (int r = 0; r < 16; ++r) part[wv][r][lane] = acc[r];
        __syncthreads();
        #pragma unroll
        for (int rr = 0; rr < 4; ++rr) {
            int r = wv * 4 + rr;
            float y1 = part[0][r][lane] + part[1][r][lane] +
                       part[2][r][lane] + part[3][r][lane] + b1v;
            h1s[r][lane] = fmaxf(y1, 0.f);
        }
        __syncthreads();
        float acc2[16];
        #pragma unroll
        for (int r = 0; r < 16; ++r) {
            const float4* xb = (const float4*)&h1s[r][wv * 16];     // uniform -> broadcast
            float a = 0.f, b = 0.f;
            #pragma unroll
            for (int i4 = 0; i4 < 4; i4 += 2) {
                float4 v0 = xb[i4], v1 = xb[i4 + 1];
                a = fmaf(v0.x, w2r[i4 * 4 + 0], a);
                a = fmaf(v0.y, w2r[i4 * 4 + 1], a);
                a = fmaf(v0.z, w2r[i4 * 4 + 2], a);
                a = fmaf(v0.w, w2r[i4 * 4 + 3], a);
                b = fmaf(v1.x, w2r[i4 * 4 + 4], b);
                b = fmaf(v1.y, w2r[i4 * 4 + 5], b);
                b = fmaf(v1.z, w2r[i4 * 4 + 6], b);
                b = fmaf(v1.w, w2r[i4 * 4 + 7], b);
            }
            acc2[r] = a + b;
        }
        __syncthreads();
        #pragma unroll
        for (int r = 0; r < 16; ++r) part[wv][r][lane] = acc2[r];
        __syncthreads();
        #pragma unroll
        for (int rr = 0; rr < 4; ++rr) {
            int r = wv * 4 + rr;
            int row = row0 + r;
            float y2 = part[0][r][lane] + part[1][r][lane] +
                       part[2][r][lane] + part[3][r][lane] + b2v;
            if (row < N_NODES) H[(size_t)row * 64 + lane] = fmaxf(y2, 0.f);
        }
        __syncthreads();
    }
}

// ---------------- gather pass: Fnew[n] = Fprev[n] - dinv[n]*sum_e w_e*Fprev[s_e]
// one wave per node, lane = feature dim; packed (src,w) records
__global__ __launch_bounds__(256) void gather_kernel(
    const float* __restrict__ Fprev, const int* __restrict__ rowp,
    const int2* __restrict__ epack, const float* __restrict__ dinv,
    float* __restrict__ Fnew)
{
    int wv = __builtin_amdgcn_readfirstlane(threadIdx.x >> 6);
    int wid = blockIdx.x * 4 + wv;   // node id (uniform)
    int lane = threadIdx.x & 63;
    int beg = rowp[wid], end = rowp[wid + 1];
    float acc = 0.0f;
    int j = beg;
    for (; j + 7 < end; j += 8) {
        int2 e0 = epack[j],     e1 = epack[j + 1], e2 = epack[j + 2], e3 = epack[j + 3];
        int2 e4 = epack[j + 4], e5 = epack[j + 5], e6 = epack[j + 6], e7 = epack[j + 7];
        float v0 = Fprev[(size_t)e0.x * 64 + lane];
        float v1 = Fprev[(size_t)e1.x * 64 + lane];
        float v2 = Fprev[(size_t)e2.x * 64 + lane];
        float v3 = Fprev[(size_t)e3.x * 64 + lane];
        float v4 = Fprev[(size_t)e4.x * 64 + lane];
        float v5 = Fprev[(size_t)e5.x * 64 + lane];
        float v6 = Fprev[(size_t)e6.x * 64 + lane];
        float v7 = Fprev[(size_t)e7.x * 64 + lane];
        acc = fmaf(v0, __int_as_float(e0.y), acc);
        acc = fmaf(v1, __int_as_float(e1.y), acc);
        acc = fmaf(v2, __int_as_float(e2.y), acc);
        acc = fmaf(v3, __int_as_float(e3.y), acc);
        acc = fmaf(v4, __int_as_float(e4.y), acc);
        acc = fmaf(v5, __int_as_float(e5.y), acc);
        acc = fmaf(v6, __int_as_float(e6.y), acc);
        acc = fmaf(v7, __int_as_float(e7.y), acc);
    }
    for (; j < end; ++j) {
        int2 e = epack[j];
        acc = fmaf(Fprev[(size_t)e.x * 64 + lane], __int_as_float(e.y), acc);
    }
    float di = dinv[wid];
    Fnew[(size_t)wid * 64 + lane] = Fprev[(size_t)wid * 64 + lane] - acc * di;
}

// ---------------- final: out = relu(sum_k Lk @ Weff[k] + bm1) @ Wm2 + bm2 ----------------
// 64 rows/block, 4 batches of 16. Wave wv owns K-slice k=wv with Weff[wv] in
// 64 VGPRs; activations LDS-staged (coalesced float4 in, broadcast b128 out).
__global__ __launch_bounds__(256) void final_kernel(
    const float* __restrict__ L0, const float* __restrict__ L1,
    const float* __restrict__ L2, const float* __restrict__ L3,
    const float* __restrict__ Weff, const float* __restrict__ Wm2,
    const float* __restrict__ bm1, const float* __restrict__ bm2,
    float* __restrict__ out)
{
    __shared__ float stage[16][4][64];   // 16 KB: [row][k][feat]
    __shared__ float part[4][16][64];    // 16 KB
    int t = threadIdx.x;
    int wv = __builtin_amdgcn_readfirstlane(t >> 6);
    int lane = t & 63;
    float wreg[64];
    #pragma unroll
    for (int i = 0; i < 64; ++i)
        wreg[i] = Weff[wv * 4096 + i * 64 + lane];
    float b1v = bm1[lane];
    float wm20 = Wm2[lane * 2 + 0], wm21 = Wm2[lane * 2 + 1];
    float bm20 = bm2[0], bm21 = bm2[1];
    const float* Ls[4] = {L0, L1, L2, L3};
    int sr = t >> 4, sc = t & 15;
    int sk = sc >> 2, so = (sc & 3) * 16;

    for (int batch = 0; batch < 4; ++batch) {
        int row0 = blockIdx.x * 64 + batch * 16;
        {
            int row = row0 + sr; if (row >= N_NODES) row = N_NODES - 1;
            const float4* s4 = (const float4*)(Ls[sk] + (size_t)row * 64 + so);
            float4* d4 = (float4*)&stage[sr][sk][so];
            #pragma unroll
            for (int q = 0; q < 4; ++q) d4[q] = s4[q];
        }
        __syncthreads();
        float acc[16];
        #pragma unroll
        for (int r = 0; r < 16; ++r) {
            const float4* xb = (const float4*)&stage[r][wv][0];   // uniform -> broadcast
            float a = 0.f, b = 0.f;
            #pragma unroll
            for (int i4 = 0; i4 < 16; i4 += 2) {
                float4 v0 = xb[i4], v1 = xb[i4 + 1];
                a = fmaf(v0.x, wreg[i4 * 4 + 0], a);
                a = fmaf(v0.y, wreg[i4 * 4 + 1], a);
                a = fmaf(v0.z, wreg[i4 * 4 + 2], a);
                a = fmaf(v0.w, wreg[i4 * 4 + 3], a);
                b = fmaf(v1.x, wreg[i4 * 4 + 4], b);
                b = fmaf(v1.y, wreg[i4 * 4 + 5], b);
                b = fmaf(v1.z, wreg[i4 * 4 + 6], b);
                b = fmaf(v1.w, wreg[i4 * 4 + 7], b);
            }
            acc[r] = a + b;
        }
        #pragma unroll
        for (int r = 0; r < 16; ++r) part[wv][r][lane] = acc[r];
        __syncthreads();
        #pragma unroll
        for (int rr = 0; rr < 4; ++rr) {
            int r = wv * 4 + rr;
            int row = row0 + r;
            float y = part[0][r][lane] + part[1][r][lane] +
                      part[2][r][lane] + part[3][r][lane] + b1v;
            y = fmaxf(y, 0.f);
            float o0 = y * wm20;
            float o1 = y * wm21;
            #pragma unroll
            for (int off = 32; off > 0; off >>= 1) {
                o0 += __shfl_down(o0, off);
                o1 += __shfl_down(o1, off);
            }
            if (lane == 0 && row < N_NODES) {
                out[row * 2 + 0] = o0 + bm20;
                out[row * 2 + 1] = o1 + bm21;
            }
        }
        __syncthreads();
    }
}

extern "C" void kernel_launch(void* const* d_in, const int* in_sizes, int n_in,
                              void* d_out, int out_size, void* d_ws, size_t ws_size,
                              hipStream_t stream)
{
    const float* feature = (const float*)d_in[0];
    const int*   src     = (const int*)d_in[1];
    const int*   dst     = (const int*)d_in[2];
    const float* W1      = (const float*)d_in[3];
    const float* b1      = (const float*)d_in[4];
    const float* W2      = (const float*)d_in[5];
    const float* b2      = (const float*)d_in[6];
    const float* thetas  = (const float*)d_in[7];
    const float* Wm1     = (const float*)d_in[8];
    const float* bm1     = (const float*)d_in[9];
    const float* Wm2     = (const float*)d_in[10];
    const float* bm2     = (const float*)d_in[11];
    float* out = (float*)d_out;

    const size_t NH = (size_t)N_NODES * H_FEATS;   // 6.4M floats
    const int NPAD = 100352;
    float* dinv   = (float*)d_ws;                   // N
    int*   degi   = (int*)(dinv + NPAD);            // N
    int*   rowp   = degi + NPAD;                    // N+1
    int*   bsums  = rowp + NPAD;                    // 512
    int*   cursor = bsums + 512;                    // N
    int2*  epack  = (int2*)(cursor + NPAD);         // E int2 (8B-aligned)
    float* L0     = (float*)(epack + N_EDGES);
    float* L1     = L0 + NH;
    float* L2     = L1 + NH;
    float* L3     = L2 + NH;
    float* Weff   = L3 + NH;                        // 16384
    // total ws use ≈ 117 MB

    hipMemsetAsync(degi,   0, N_NODES * sizeof(int), stream);
    hipMemsetAsync(cursor, 0, N_NODES * sizeof(int), stream);

    hist_kernel<<<1024, 256, 0, stream>>>(dst, degi);
    dinv_kernel<<<(N_NODES + 255) / 256, 256, 0, stream>>>(degi, dinv);
    scan1_kernel<<<SCAN_BLOCKS, 256, 0, stream>>>(degi, rowp, bsums);
    scan2_kernel<<<1, 512, 0, stream>>>(bsums);
    scan3_kernel<<<SCAN_BLOCKS, 256, 0, stream>>>(rowp, bsums);
    fill_kernel<<<2048, 256, 0, stream>>>(src, dst, rowp, dinv, cursor, epack);

    weff_kernel<<<64, 256, 0, stream>>>(thetas, Wm1, Weff);
    trunk_kernel<<<1563, 256, 0, stream>>>(feature, W1, b1, W2, b2, L0);

    float* Ls[4] = {L0, L1, L2, L3};
    for (int k = 1; k <= 3; ++k)
        gather_kernel<<<25000, 256, 0, stream>>>(Ls[k - 1], rowp, epack, dinv, Ls[k]);

    final_kernel<<<1563, 256, 0, stream>>>(L0, L1, L2, L3, Weff, Wm2, bm1, bm2, out);
}